// Round 1
// baseline (103.187 us; speedup 1.0000x reference)
//
#include <hip/hip_runtime.h>

#define NGAUSS 2048
#define NPIX   65536
#define WID    512.0f
#define HEI    512.0f
#define NSLICE 16                // N-dimension split for occupancy
#define GPB    (NGAUSS / NSLICE) // 128 gaussians per block
#define TPB    256               // threads per block
#define PPT    2                 // pixels per thread
#define PPB    (TPB * PPT)       // 512 pixels per block

// Per-gaussian packed params in LDS (2 x float4 + 1 float = 36 B):
// c0 = (A, B, C, D) ; c1 = (E0, E1, r, g) ; shb = b
// dx = A*X + B*Y + E0 ; dy = C*X + D*Y + E1 ; w = exp2(-(dx^2+dy^2))
// A..E pre-scaled by sqrt(log2(e)) so exp(-q) == exp2(-q_scaled).

__global__ __launch_bounds__(256) void splat_kernel(
    const float2* __restrict__ x, const float* __restrict__ rgb,
    const float* __restrict__ mu, const float* __restrict__ scale,
    const float* __restrict__ angle, float* __restrict__ out)
{
    __shared__ float4 sh4[GPB * 2];  // 4 KiB
    __shared__ float  shb[GPB];      // 0.5 KiB

    const int slice = blockIdx.x & (NSLICE - 1);
    const int pg    = blockIdx.x >> 4;          // pixel group 0..127
    const int tid   = threadIdx.x;

    // ---- fused prep: thread tid preps gaussian (slice*GPB + tid) ----
    if (tid < GPB) {
        const float MU_BORDER = 1.05f;
        const float S_MIN = 1.0f / 30.0f;
        const float S_MAX = 1.0f / 0.75f;
        const float PI_APPROX = 3.1416f;
        const float K = 1.2011224087864498f;  // sqrt(log2(e))

        int n = slice * GPB + tid;
        float mx = tanhf(mu[2*n+0]) * MU_BORDER * (0.5f * WID);
        float my = tanhf(mu[2*n+1]) * MU_BORDER * (0.5f * HEI);
        float al = tanhf(angle[n]) * PI_APPROX;
        float c = cosf(al);
        float s = sinf(al);
        float S0 = 1.0f / (1.0f + expf(-scale[2*n+0])) * (S_MAX - S_MIN) + S_MIN;
        float S1 = 1.0f / (1.0f + expf(-scale[2*n+1])) * (S_MAX - S_MIN) + S_MIN;

        float A  =  S0 * c * K;
        float Bc = -(S0 * s * K);
        float C  =  S1 * s * K;
        float D  =  S1 * c * K;
        float E0 = -(A * mx + Bc * my);
        float E1 = -(C * mx + D  * my);

        float r = 1.0f / (1.0f + expf(-rgb[3*n+0]));
        float g = 1.0f / (1.0f + expf(-rgb[3*n+1]));
        float b = 1.0f / (1.0f + expf(-rgb[3*n+2]));

        sh4[2*tid + 0] = make_float4(A, Bc, C, D);
        sh4[2*tid + 1] = make_float4(E0, E1, r, g);
        shb[tid] = b;
    }
    __syncthreads();

    // ---- splat: two pixels per thread over this block's 128 gaussians ----
    const int t0 = pg * PPB + tid;
    const int t1 = t0 + TPB;
    float2 xy0 = x[t0];
    float2 xy1 = x[t1];
    float X0 = xy0.x - 0.5f * WID, Y0 = xy0.y - 0.5f * HEI;
    float X1 = xy1.x - 0.5f * WID, Y1 = xy1.y - 0.5f * HEI;

    float ar0 = 0.f, ag0 = 0.f, ab0 = 0.f;
    float ar1 = 0.f, ag1 = 0.f, ab1 = 0.f;
    #pragma unroll 4
    for (int j = 0; j < GPB; ++j) {
        float4 c0 = sh4[2*j + 0];
        float4 c1 = sh4[2*j + 1];
        float bb  = shb[j];

        float dx0 = fmaf(c0.x, X0, fmaf(c0.y, Y0, c1.x));
        float dy0 = fmaf(c0.z, X0, fmaf(c0.w, Y0, c1.y));
        float q0  = fmaf(dx0, dx0, dy0 * dy0);
        float w0  = __builtin_amdgcn_exp2f(-q0);

        float dx1 = fmaf(c0.x, X1, fmaf(c0.y, Y1, c1.x));
        float dy1 = fmaf(c0.z, X1, fmaf(c0.w, Y1, c1.y));
        float q1  = fmaf(dx1, dx1, dy1 * dy1);
        float w1  = __builtin_amdgcn_exp2f(-q1);

        ar0 = fmaf(w0, c1.z, ar0);
        ag0 = fmaf(w0, c1.w, ag0);
        ab0 = fmaf(w0, bb,   ab0);
        ar1 = fmaf(w1, c1.z, ar1);
        ag1 = fmaf(w1, c1.w, ag1);
        ab1 = fmaf(w1, bb,   ab1);
    }

    atomicAdd(&out[3*t0 + 0], ar0);
    atomicAdd(&out[3*t0 + 1], ag0);
    atomicAdd(&out[3*t0 + 2], ab0);
    atomicAdd(&out[3*t1 + 0], ar1);
    atomicAdd(&out[3*t1 + 1], ag1);
    atomicAdd(&out[3*t1 + 2], ab1);
}

extern "C" void kernel_launch(void* const* d_in, const int* in_sizes, int n_in,
                              void* d_out, int out_size, void* d_ws, size_t ws_size,
                              hipStream_t stream) {
    const float* x     = (const float*)d_in[0];  // [B,2]
    const float* rgb   = (const float*)d_in[1];  // [N,3]
    const float* mu    = (const float*)d_in[2];  // [N,2]
    const float* scale = (const float*)d_in[3];  // [N,2]
    const float* angle = (const float*)d_in[4];  // [N]

    // harness poisons d_out with 0xAA — zero it (async, graph-capture safe)
    hipMemsetAsync(d_out, 0, (size_t)out_size * sizeof(float), stream);

    hipLaunchKernelGGL(splat_kernel, dim3(NPIX / PPB * NSLICE), dim3(256), 0, stream,
                       (const float2*)x, rgb, mu, scale, angle, (float*)d_out);
}

// Round 2
// 97.319 us; speedup vs baseline: 1.0603x; 1.0603x over previous
//
#include <hip/hip_runtime.h>

#define NGAUSS 2048
#define NPIX   65536
#define WID    512.0f
#define HEI    512.0f
#define NSLICE 16                // N-dimension split for occupancy
#define GPB    (NGAUSS / NSLICE) // 128 gaussians per block
#define TPB    256               // threads per block
#define PPT    2                 // pixels per thread (one packed pair)
#define PPB    (TPB * PPT)       // 512 pixels per block

typedef float v2f __attribute__((ext_vector_type(2)));

// Per-gaussian packed params in LDS (2 x float4 + 1 float = 36 B):
// c0 = (A, B, C, D) ; c1 = (E0, E1, r, g) ; shb = b
// dx = A*X + B*Y + E0 ; dy = C*X + D*Y + E1 ; w = exp2(-(dx^2+dy^2))
// A..E pre-scaled by sqrt(log2(e)) so exp(-q) == exp2(-q_scaled).
// Inner loop is packed fp32: the 2 pixels of a thread ride in a
// <2 x float> so dx/dy/q/accum become v_pk_fma_f32 (halves VALU issue).

__global__ __launch_bounds__(256) void splat_kernel(
    const float2* __restrict__ x, const float* __restrict__ rgb,
    const float* __restrict__ mu, const float* __restrict__ scale,
    const float* __restrict__ angle, float* __restrict__ out)
{
    __shared__ float4 sh4[GPB * 2];  // 4 KiB
    __shared__ float  shb[GPB];      // 0.5 KiB

    const int slice = blockIdx.x & (NSLICE - 1);
    const int pg    = blockIdx.x >> 4;          // pixel group 0..127
    const int tid   = threadIdx.x;

    // ---- fused prep: thread tid preps gaussian (slice*GPB + tid) ----
    if (tid < GPB) {
        const float MU_BORDER = 1.05f;
        const float S_MIN = 1.0f / 30.0f;
        const float S_MAX = 1.0f / 0.75f;
        const float PI_APPROX = 3.1416f;
        const float K = 1.2011224087864498f;  // sqrt(log2(e))

        int n = slice * GPB + tid;
        float mx = tanhf(mu[2*n+0]) * MU_BORDER * (0.5f * WID);
        float my = tanhf(mu[2*n+1]) * MU_BORDER * (0.5f * HEI);
        float al = tanhf(angle[n]) * PI_APPROX;
        float c = cosf(al);
        float s = sinf(al);
        float S0 = 1.0f / (1.0f + expf(-scale[2*n+0])) * (S_MAX - S_MIN) + S_MIN;
        float S1 = 1.0f / (1.0f + expf(-scale[2*n+1])) * (S_MAX - S_MIN) + S_MIN;

        float A  =  S0 * c * K;
        float Bc = -(S0 * s * K);
        float C  =  S1 * s * K;
        float D  =  S1 * c * K;
        float E0 = -(A * mx + Bc * my);
        float E1 = -(C * mx + D  * my);

        float r = 1.0f / (1.0f + expf(-rgb[3*n+0]));
        float g = 1.0f / (1.0f + expf(-rgb[3*n+1]));
        float b = 1.0f / (1.0f + expf(-rgb[3*n+2]));

        sh4[2*tid + 0] = make_float4(A, Bc, C, D);
        sh4[2*tid + 1] = make_float4(E0, E1, r, g);
        shb[tid] = b;
    }
    __syncthreads();

    // ---- splat: two pixels per thread (packed) over 128 gaussians ----
    const int t0 = pg * PPB + tid;
    const int t1 = t0 + TPB;
    float2 xy0 = x[t0];
    float2 xy1 = x[t1];
    v2f Xv = {xy0.x - 0.5f * WID, xy1.x - 0.5f * WID};
    v2f Yv = {xy0.y - 0.5f * HEI, xy1.y - 0.5f * HEI};

    v2f arv = {0.f, 0.f}, agv = {0.f, 0.f}, abv = {0.f, 0.f};
    #pragma unroll 4
    for (int j = 0; j < GPB; ++j) {
        float4 c0 = sh4[2*j + 0];
        float4 c1 = sh4[2*j + 1];
        float bb  = shb[j];

        v2f Av  = {c0.x, c0.x};
        v2f Bv  = {c0.y, c0.y};
        v2f Cv  = {c0.z, c0.z};
        v2f Dv  = {c0.w, c0.w};
        v2f E0v = {c1.x, c1.x};
        v2f E1v = {c1.y, c1.y};

        v2f dx = __builtin_elementwise_fma(Av, Xv,
                 __builtin_elementwise_fma(Bv, Yv, E0v));
        v2f dy = __builtin_elementwise_fma(Cv, Xv,
                 __builtin_elementwise_fma(Dv, Yv, E1v));
        // qn = -(dx*dx + dy*dy), negations fold into fma/mul modifiers
        v2f qn = __builtin_elementwise_fma(dx, -dx, (-dy) * dy);

        v2f wv;
        wv.x = __builtin_amdgcn_exp2f(qn.x);
        wv.y = __builtin_amdgcn_exp2f(qn.y);

        v2f rv = {c1.z, c1.z};
        v2f gv = {c1.w, c1.w};
        v2f bv = {bb,   bb};
        arv = __builtin_elementwise_fma(wv, rv, arv);
        agv = __builtin_elementwise_fma(wv, gv, agv);
        abv = __builtin_elementwise_fma(wv, bv, abv);
    }

    atomicAdd(&out[3*t0 + 0], arv.x);
    atomicAdd(&out[3*t0 + 1], agv.x);
    atomicAdd(&out[3*t0 + 2], abv.x);
    atomicAdd(&out[3*t1 + 0], arv.y);
    atomicAdd(&out[3*t1 + 1], agv.y);
    atomicAdd(&out[3*t1 + 2], abv.y);
}

extern "C" void kernel_launch(void* const* d_in, const int* in_sizes, int n_in,
                              void* d_out, int out_size, void* d_ws, size_t ws_size,
                              hipStream_t stream) {
    const float* x     = (const float*)d_in[0];  // [B,2]
    const float* rgb   = (const float*)d_in[1];  // [N,3]
    const float* mu    = (const float*)d_in[2];  // [N,2]
    const float* scale = (const float*)d_in[3];  // [N,2]
    const float* angle = (const float*)d_in[4];  // [N]

    // harness poisons d_out with 0xAA — zero it (async, graph-capture safe)
    hipMemsetAsync(d_out, 0, (size_t)out_size * sizeof(float), stream);

    hipLaunchKernelGGL(splat_kernel, dim3(NPIX / PPB * NSLICE), dim3(256), 0, stream,
                       (const float2*)x, rgb, mu, scale, angle, (float*)d_out);
}